// Round 6
// baseline (50.841 us; speedup 1.0000x reference)
//
#include <hip/hip_runtime.h>
#include <cmath>

#define V 50257
#define H 1024
#define RPB 8                            // rows per logits block
#define NB_LOGITS ((V + RPB - 1) / RPB)  // 6283 blocks, 8 rows each
#define NB_NORM ((V + 255) / 256)        // 197 blocks

// ws layout (floats):
// [0, H)                  h1
// [H, H + 2*NB_LOGITS)    per-block (max, sumexp) partials, as float2

__device__ __forceinline__ float dot4(float4 a, float4 b) {
    return a.x * b.x + a.y * b.y + a.z * b.z + a.w * b.w;
}

__device__ __forceinline__ void lse_merge(float& m, float& s, float mo, float so) {
    const float mn = fmaxf(m, mo);
    s = s * __expf(m - mn) + so * __expf(mo - mn);
    m = mn;
}

// Block j computes the 4 gate dots for hidden unit j (wave w -> gate row w*H+j),
// then finishes the LSTM cell in-block. h1 -> ws, h1/c1 -> out tail.
__global__ __launch_bounds__(256) void k_gates_cell(const int* __restrict__ token,
                                                    const float* __restrict__ h0,
                                                    const float* __restrict__ c0,
                                                    const float* __restrict__ emb,
                                                    const float* __restrict__ W_ih,
                                                    const float* __restrict__ W_hh,
                                                    const float* __restrict__ b_ih,
                                                    const float* __restrict__ b_hh,
                                                    float* __restrict__ out,
                                                    float* __restrict__ h1ws) {
    const int tid = threadIdx.x;
    const int wid = tid >> 6, lane = tid & 63;
    const int j = blockIdx.x;           // hidden unit
    const int row = wid * H + j;        // gate row: wave 0..3 -> i,f,g,o
    const int tok = token[0];

    const float4* x4 = (const float4*)(emb + (size_t)tok * H);
    const float4* h4 = (const float4*)h0;
    const float4* wi = (const float4*)(W_ih + (size_t)row * H);
    const float4* wh = (const float4*)(W_hh + (size_t)row * H);

    float4 wiv[4], whv[4], xv[4], hv[4];
#pragma unroll
    for (int it = 0; it < 4; ++it) {
        const int k4 = it * 64 + lane;
        wiv[it] = wi[k4];
        whv[it] = wh[k4];
        xv[it]  = x4[k4];
        hv[it]  = h4[k4];
    }

    float acc = 0.f;
#pragma unroll
    for (int it = 0; it < 4; ++it) {
        float4 x = xv[it];
        x.x = fmaxf(x.x, 0.f); x.y = fmaxf(x.y, 0.f);
        x.z = fmaxf(x.z, 0.f); x.w = fmaxf(x.w, 0.f);
        acc += dot4(wiv[it], x);
        acc += dot4(whv[it], hv[it]);
    }
#pragma unroll
    for (int off = 32; off; off >>= 1) acc += __shfl_xor(acc, off);

    __shared__ float gsh[4];
    if (lane == 0) gsh[wid] = acc + b_ih[row] + b_hh[row];
    __syncthreads();
    if (tid == 0) {
        const float gi = gsh[0], gf = gsh[1], gg = gsh[2], go = gsh[3];
        const float si = 1.f / (1.f + __expf(-gi));
        const float sf = 1.f / (1.f + __expf(-gf));
        const float so = 1.f / (1.f + __expf(-go));
        const float c1 = sf * c0[j] + si * tanhf(gg);
        const float h1 = so * tanhf(c1);
        out[V + j]     = h1;
        out[V + H + j] = c1;
        h1ws[j]        = h1;
    }
}

// logits[row] = dot(W_out[row], h1) + b_out[row]; 2 rows/wave, 8 rows/block.
// Lower VGPR (~60) -> 8 waves/SIMD; 6283 blocks -> ~24.5/CU for a small tail.
__global__ __launch_bounds__(256) void k_logits(const float* __restrict__ h1,
                                                const float* __restrict__ W_out,
                                                const float* __restrict__ b_out,
                                                float* __restrict__ out,
                                                float2* __restrict__ partials) {
    const int tid = threadIdx.x;
    const int wid = tid >> 6, lane = tid & 63;

    __shared__ float arr[RPB][64];   // [local row][lane] partials
    __shared__ float blk[RPB];

    float4 hv[4];
    const float4* h4 = (const float4*)h1;
#pragma unroll
    for (int it = 0; it < 4; ++it) hv[it] = h4[it * 64 + lane];

    const int row0 = blockIdx.x * RPB;
    const int wrow0 = row0 + wid * 2;

    // prefetch both rows' fragments (clamped rows stay in-bounds; masked later)
    float4 w[2][4];
#pragma unroll
    for (int r = 0; r < 2; ++r) {
        const int rr = min(wrow0 + r, V - 1);
        const float4* wp = (const float4*)(W_out + (size_t)rr * H);
#pragma unroll
        for (int it = 0; it < 4; ++it) w[r][it] = wp[it * 64 + lane];
    }

#pragma unroll
    for (int r = 0; r < 2; ++r) {
        const float acc = dot4(w[r][0], hv[0]) + dot4(w[r][1], hv[1]) +
                          dot4(w[r][2], hv[2]) + dot4(w[r][3], hv[3]);
        arr[wid * 2 + r][lane] = acc;
    }
    __syncthreads();

    // reduce: 8 groups of 32 threads; group g sums row g's 64 partials.
    // (offsets <=16 keep shuffles inside each 32-lane half of a wave)
    {
        const int g = tid >> 5, i = tid & 31;
        const float2 p = ((const float2*)arr[g])[i];
        float v = p.x + p.y;
#pragma unroll
        for (int off = 16; off; off >>= 1) v += __shfl_xor(v, off);
        if (i == 0) {
            const int row = row0 + g;
            if (row < V) {
                const float l = v + b_out[row];
                out[row] = l;
                blk[g] = l;
            } else {
                blk[g] = -INFINITY;
            }
        }
    }
    __syncthreads();

    // tail: wave 0, lanes 0..7 -> per-block (max, sumexp)
    if (wid == 0 && lane < 8) {
        float v = blk[lane];
        float m = v;
#pragma unroll
        for (int off = 4; off; off >>= 1) m = fmaxf(m, __shfl_xor(m, off));
        float e = __expf(v - m);
#pragma unroll
        for (int off = 4; off; off >>= 1) e += __shfl_xor(e, off);
        if (lane == 0) partials[blockIdx.x] = make_float2(m, e);
    }
}

// Each block redundantly merges all partials (L2-hot, 50 KB) then subtracts
// the log-sum-exp from its 256 output elements.
__global__ __launch_bounds__(256) void k_norm(const float2* __restrict__ partials,
                                              float* __restrict__ out) {
    const int tid = threadIdx.x;
    const int wid = tid >> 6, lane = tid & 63;

    float m = -INFINITY, s = 0.f;
    for (int i = tid; i < NB_LOGITS; i += 256) {
        const float2 p = partials[i];
        lse_merge(m, s, p.x, p.y);
    }
#pragma unroll
    for (int off = 32; off; off >>= 1) {
        const float mo = __shfl_xor(m, off), so = __shfl_xor(s, off);
        lse_merge(m, s, mo, so);
    }
    __shared__ float cm[4], cs[4], st_sh;
    if (lane == 0) { cm[wid] = m; cs[wid] = s; }
    __syncthreads();
    if (tid == 0) {
        float M = cm[0], S = cs[0];
#pragma unroll
        for (int w = 1; w < 4; ++w) lse_merge(M, S, cm[w], cs[w]);
        st_sh = M + __logf(S);
    }
    __syncthreads();
    const float st = st_sh;
    const int i = blockIdx.x * 256 + tid;
    if (i < V) out[i] -= st;
}

extern "C" void kernel_launch(void* const* d_in, const int* in_sizes, int n_in,
                              void* d_out, int out_size, void* d_ws, size_t ws_size,
                              hipStream_t stream) {
    const int*   token = (const int*)d_in[0];
    const float* h0    = (const float*)d_in[1];
    const float* c0    = (const float*)d_in[2];
    const float* emb   = (const float*)d_in[3];
    const float* W_ih  = (const float*)d_in[4];
    const float* W_hh  = (const float*)d_in[5];
    const float* b_ih  = (const float*)d_in[6];
    const float* b_hh  = (const float*)d_in[7];
    const float* W_out = (const float*)d_in[8];
    const float* b_out = (const float*)d_in[9];

    float* out = (float*)d_out;
    float* ws  = (float*)d_ws;
    float* h1ws      = ws;
    float2* partials = (float2*)(ws + H);

    k_gates_cell<<<H, 256, 0, stream>>>(token, h0, c0, emb, W_ih, W_hh, b_ih, b_hh, out, h1ws);
    k_logits<<<NB_LOGITS, 256, 0, stream>>>(h1ws, W_out, b_out, out, partials);
    k_norm<<<NB_NORM, 256, 0, stream>>>(partials, out);
}

// Round 7
// 47.877 us; speedup vs baseline: 1.0619x; 1.0619x over previous
//
#include <hip/hip_runtime.h>
#include <cmath>

#define V 50257
#define H 1024
#define NB_LOGITS ((V + 15) / 16)      // 3142 blocks, 16 rows each
#define NB_NORM ((V + 255) / 256)      // 197 blocks

// ws layout (floats):
// [0, H)                  h1
// [H, H + 2*NB_LOGITS)    per-block (max, sumexp) partials, as float2

__device__ __forceinline__ float dot4(float4 a, float4 b) {
    return a.x * b.x + a.y * b.y + a.z * b.z + a.w * b.w;
}

__device__ __forceinline__ void lse_merge(float& m, float& s, float mo, float so) {
    const float mn = fmaxf(m, mo);
    s = s * __expf(m - mn) + so * __expf(mo - mn);
    m = mn;
}

// Block j computes the 4 gate dots for hidden unit j (wave w -> gate row w*H+j),
// then finishes the LSTM cell in-block. h1 -> ws, h1/c1 -> out tail.
__global__ __launch_bounds__(256) void k_gates_cell(const int* __restrict__ token,
                                                    const float* __restrict__ h0,
                                                    const float* __restrict__ c0,
                                                    const float* __restrict__ emb,
                                                    const float* __restrict__ W_ih,
                                                    const float* __restrict__ W_hh,
                                                    const float* __restrict__ b_ih,
                                                    const float* __restrict__ b_hh,
                                                    float* __restrict__ out,
                                                    float* __restrict__ h1ws) {
    const int tid = threadIdx.x;
    const int wid = tid >> 6, lane = tid & 63;
    const int j = blockIdx.x;           // hidden unit
    const int row = wid * H + j;        // gate row: wave 0..3 -> i,f,g,o
    const int tok = token[0];

    const float4* x4 = (const float4*)(emb + (size_t)tok * H);
    const float4* h4 = (const float4*)h0;
    const float4* wi = (const float4*)(W_ih + (size_t)row * H);
    const float4* wh = (const float4*)(W_hh + (size_t)row * H);

    float4 wiv[4], whv[4], xv[4], hv[4];
#pragma unroll
    for (int it = 0; it < 4; ++it) {
        const int k4 = it * 64 + lane;
        wiv[it] = wi[k4];
        whv[it] = wh[k4];
        xv[it]  = x4[k4];
        hv[it]  = h4[k4];
    }

    float acc = 0.f;
#pragma unroll
    for (int it = 0; it < 4; ++it) {
        float4 x = xv[it];
        x.x = fmaxf(x.x, 0.f); x.y = fmaxf(x.y, 0.f);
        x.z = fmaxf(x.z, 0.f); x.w = fmaxf(x.w, 0.f);
        acc += dot4(wiv[it], x);
        acc += dot4(whv[it], hv[it]);
    }
#pragma unroll
    for (int off = 32; off; off >>= 1) acc += __shfl_xor(acc, off);

    __shared__ float gsh[4];
    if (lane == 0) gsh[wid] = acc + b_ih[row] + b_hh[row];
    __syncthreads();
    if (tid == 0) {
        const float gi = gsh[0], gf = gsh[1], gg = gsh[2], go = gsh[3];
        const float si = 1.f / (1.f + __expf(-gi));
        const float sf = 1.f / (1.f + __expf(-gf));
        const float so = 1.f / (1.f + __expf(-go));
        const float c1 = sf * c0[j] + si * tanhf(gg);
        const float h1 = so * tanhf(c1);
        out[V + j]     = h1;
        out[V + H + j] = c1;
        h1ws[j]        = h1;
    }
}

// logits[row] = dot(W_out[row], h1) + b_out[row]; 4 rows/wave, 16 rows/block.
// Cross-lane reduction via LDS transpose.
__global__ __launch_bounds__(256) void k_logits(const float* __restrict__ h1,
                                                const float* __restrict__ W_out,
                                                const float* __restrict__ b_out,
                                                float* __restrict__ out,
                                                float2* __restrict__ partials) {
    const int tid = threadIdx.x;
    const int wid = tid >> 6, lane = tid & 63;

    __shared__ float arr[16 * 64];   // [local row][lane] partials
    __shared__ float blk[16];

    float4 hv[4];
    const float4* h4 = (const float4*)h1;
#pragma unroll
    for (int it = 0; it < 4; ++it) hv[it] = h4[it * 64 + lane];

    const int row0 = blockIdx.x * 16;
    const int wrow0 = row0 + wid * 4;

    // prefetch all 16 row-fragments (clamped rows stay in-bounds; masked later)
    float4 w[4][4];
#pragma unroll
    for (int r = 0; r < 4; ++r) {
        const int rr = min(wrow0 + r, V - 1);
        const float4* wp = (const float4*)(W_out + (size_t)rr * H);
#pragma unroll
        for (int it = 0; it < 4; ++it) w[r][it] = wp[it * 64 + lane];
    }

    // 4 independent per-lane row partials
#pragma unroll
    for (int r = 0; r < 4; ++r) {
        const float acc = dot4(w[r][0], hv[0]) + dot4(w[r][1], hv[1]) +
                          dot4(w[r][2], hv[2]) + dot4(w[r][3], hv[3]);
        arr[(wid * 4 + r) * 64 + lane] = acc;
    }
    __syncthreads();

    // transpose reduce: group g (16 lanes) sums local row g's 64 partials
    {
        const int g = tid >> 4, i = tid & 15;
        const float4 p = ((const float4*)arr)[g * 16 + i];
        float v = (p.x + p.y) + (p.z + p.w);
#pragma unroll
        for (int off = 8; off; off >>= 1) v += __shfl_xor(v, off);
        if (i == 0) {
            const int row = row0 + g;
            if (row < V) {
                const float l = v + b_out[row];
                out[row] = l;
                blk[g] = l;
            } else {
                blk[g] = -INFINITY;
            }
        }
    }
    __syncthreads();

    // parallel tail: wave 0, lanes 0..15 -> per-block (max, sumexp)
    if (wid == 0 && lane < 16) {
        float v = blk[lane];
        float m = v;
#pragma unroll
        for (int off = 8; off; off >>= 1) m = fmaxf(m, __shfl_xor(m, off));
        float e = __expf(v - m);
#pragma unroll
        for (int off = 8; off; off >>= 1) e += __shfl_xor(e, off);
        if (lane == 0) partials[blockIdx.x] = make_float2(m, e);
    }
}

// Each block redundantly merges all partials (L2-hot, 25 KB) then subtracts
// the log-sum-exp from its 256 output elements.
__global__ __launch_bounds__(256) void k_norm(const float2* __restrict__ partials,
                                              float* __restrict__ out) {
    const int tid = threadIdx.x;
    const int wid = tid >> 6, lane = tid & 63;

    float m = -INFINITY, s = 0.f;
    for (int i = tid; i < NB_LOGITS; i += 256) {
        const float2 p = partials[i];
        lse_merge(m, s, p.x, p.y);
    }
#pragma unroll
    for (int off = 32; off; off >>= 1) {
        const float mo = __shfl_xor(m, off), so = __shfl_xor(s, off);
        lse_merge(m, s, mo, so);
    }
    __shared__ float cm[4], cs[4], st_sh;
    if (lane == 0) { cm[wid] = m; cs[wid] = s; }
    __syncthreads();
    if (tid == 0) {
        float M = cm[0], S = cs[0];
#pragma unroll
        for (int w = 1; w < 4; ++w) lse_merge(M, S, cm[w], cs[w]);
        st_sh = M + __logf(S);
    }
    __syncthreads();
    const float st = st_sh;
    const int i = blockIdx.x * 256 + tid;
    if (i < V) out[i] -= st;
}

extern "C" void kernel_launch(void* const* d_in, const int* in_sizes, int n_in,
                              void* d_out, int out_size, void* d_ws, size_t ws_size,
                              hipStream_t stream) {
    const int*   token = (const int*)d_in[0];
    const float* h0    = (const float*)d_in[1];
    const float* c0    = (const float*)d_in[2];
    const float* emb   = (const float*)d_in[3];
    const float* W_ih  = (const float*)d_in[4];
    const float* W_hh  = (const float*)d_in[5];
    const float* b_ih  = (const float*)d_in[6];
    const float* b_hh  = (const float*)d_in[7];
    const float* W_out = (const float*)d_in[8];
    const float* b_out = (const float*)d_in[9];

    float* out = (float*)d_out;
    float* ws  = (float*)d_ws;
    float* h1ws      = ws;
    float2* partials = (float2*)(ws + H);

    k_gates_cell<<<H, 256, 0, stream>>>(token, h0, c0, emb, W_ih, W_hh, b_ih, b_hh, out, h1ws);
    k_logits<<<NB_LOGITS, 256, 0, stream>>>(h1ws, W_out, b_out, out, partials);
    k_norm<<<NB_NORM, 256, 0, stream>>>(partials, out);
}

// Round 8
// 45.747 us; speedup vs baseline: 1.1113x; 1.0466x over previous
//
#include <hip/hip_runtime.h>
#include <cmath>

#define V 50257
#define H 1024
#define NBL 3072                       // logits blocks: exactly 12 per CU (256 CUs)
#define NB_NORM ((V + 255) / 256)      // 197 blocks

// ws layout (floats):
// [0, H)             h1
// [H, H + 2*NBL)     per-block (max, sumexp) partials, as float2

__device__ __forceinline__ float dot4(float4 a, float4 b) {
    return a.x * b.x + a.y * b.y + a.z * b.z + a.w * b.w;
}

__device__ __forceinline__ void lse_merge(float& m, float& s, float mo, float so) {
    const float mn = fmaxf(m, mo);
    s = s * __expf(m - mn) + so * __expf(mo - mn);
    m = mn;
}

// Block j computes the 4 gate dots for hidden unit j (wave w -> gate row w*H+j),
// then finishes the LSTM cell in-block. h1 -> ws, h1/c1 -> out tail.
__global__ __launch_bounds__(256) void k_gates_cell(const int* __restrict__ token,
                                                    const float* __restrict__ h0,
                                                    const float* __restrict__ c0,
                                                    const float* __restrict__ emb,
                                                    const float* __restrict__ W_ih,
                                                    const float* __restrict__ W_hh,
                                                    const float* __restrict__ b_ih,
                                                    const float* __restrict__ b_hh,
                                                    float* __restrict__ out,
                                                    float* __restrict__ h1ws) {
    const int tid = threadIdx.x;
    const int wid = tid >> 6, lane = tid & 63;
    const int j = blockIdx.x;           // hidden unit
    const int row = wid * H + j;        // gate row: wave 0..3 -> i,f,g,o
    const int tok = token[0];

    const float4* x4 = (const float4*)(emb + (size_t)tok * H);
    const float4* h4 = (const float4*)h0;
    const float4* wi = (const float4*)(W_ih + (size_t)row * H);
    const float4* wh = (const float4*)(W_hh + (size_t)row * H);

    float4 wiv[4], whv[4], xv[4], hv[4];
#pragma unroll
    for (int it = 0; it < 4; ++it) {
        const int k4 = it * 64 + lane;
        wiv[it] = wi[k4];
        whv[it] = wh[k4];
        xv[it]  = x4[k4];
        hv[it]  = h4[k4];
    }

    float acc = 0.f;
#pragma unroll
    for (int it = 0; it < 4; ++it) {
        float4 x = xv[it];
        x.x = fmaxf(x.x, 0.f); x.y = fmaxf(x.y, 0.f);
        x.z = fmaxf(x.z, 0.f); x.w = fmaxf(x.w, 0.f);
        acc += dot4(wiv[it], x);
        acc += dot4(whv[it], hv[it]);
    }
#pragma unroll
    for (int off = 32; off; off >>= 1) acc += __shfl_xor(acc, off);

    __shared__ float gsh[4];
    if (lane == 0) gsh[wid] = acc + b_ih[row] + b_hh[row];
    __syncthreads();
    if (tid == 0) {
        const float gi = gsh[0], gf = gsh[1], gg = gsh[2], go = gsh[3];
        const float si = 1.f / (1.f + __expf(-gi));
        const float sf = 1.f / (1.f + __expf(-gf));
        const float so = 1.f / (1.f + __expf(-go));
        const float c1 = sf * c0[j] + si * tanhf(gg);
        const float h1 = so * tanhf(c1);
        out[V + j]     = h1;
        out[V + H + j] = c1;
        h1ws[j]        = h1;
    }
}

// logits[row] = dot(W_out[row], h1) + b_out[row].
// Grid = 3072 (exactly 12 blocks/CU): block handles rows [bid*V/NBL, (bid+1)*V/NBL),
// i.e. 16 or 17 rows -> zero tail-round quantization across CUs.
__global__ __launch_bounds__(256) void k_logits(const float* __restrict__ h1,
                                                const float* __restrict__ W_out,
                                                const float* __restrict__ b_out,
                                                float* __restrict__ out,
                                                float2* __restrict__ partials) {
    const int tid = threadIdx.x;
    const int wid = tid >> 6, lane = tid & 63;
    const int bid = blockIdx.x;

    __shared__ float arr[17 * 64];   // [local slot][lane] partials
    __shared__ float blk[17];

    float4 hv[4];
    const float4* h4 = (const float4*)h1;
#pragma unroll
    for (int it = 0; it < 4; ++it) hv[it] = h4[it * 64 + lane];

    const int start = (int)(((long long)bid * V) / NBL);
    const int end   = (int)(((long long)(bid + 1) * V) / NBL);
    const int n = end - start;          // 16 or 17

    // prefetch 4 rows for this wave: slots wid, wid+4, wid+8, wid+12 (always < 16 <= n)
    float4 w[4][4];
#pragma unroll
    for (int r = 0; r < 4; ++r) {
        const int row = start + wid + 4 * r;
        const float4* wp = (const float4*)(W_out + (size_t)row * H);
#pragma unroll
        for (int it = 0; it < 4; ++it) w[r][it] = wp[it * 64 + lane];
    }

#pragma unroll
    for (int r = 0; r < 4; ++r) {
        const float acc = dot4(w[r][0], hv[0]) + dot4(w[r][1], hv[1]) +
                          dot4(w[r][2], hv[2]) + dot4(w[r][3], hv[3]);
        arr[(wid + 4 * r) * 64 + lane] = acc;
    }

    // 17th row (slot 16), handled by a rotating wave; registers reused post-store
    if (n == 17 && wid == (bid & 3)) {
        const float4* wp = (const float4*)(W_out + (size_t)(start + 16) * H);
        float4 e0 = wp[lane], e1 = wp[64 + lane], e2 = wp[128 + lane], e3 = wp[192 + lane];
        const float acc = dot4(e0, hv[0]) + dot4(e1, hv[1]) + dot4(e2, hv[2]) + dot4(e3, hv[3]);
        arr[16 * 64 + lane] = acc;
    }
    __syncthreads();

    // transpose reduce: group g (16 lanes) sums slot g's 64 partials
    {
        const int g = tid >> 4, i = tid & 15;
        const float4 p = ((const float4*)arr)[g * 16 + i];
        float v = (p.x + p.y) + (p.z + p.w);
#pragma unroll
        for (int off = 8; off; off >>= 1) v += __shfl_xor(v, off);
        if (i == 0) {
            const int row = start + g;
            const float l = v + b_out[row];
            out[row] = l;
            blk[g] = l;
        }
    }
    if (n == 17 && tid < 16) {
        const float4 p = ((const float4*)arr)[16 * 16 + tid];
        float v = (p.x + p.y) + (p.z + p.w);
#pragma unroll
        for (int off = 8; off; off >>= 1) v += __shfl_xor(v, off);
        if (tid == 0) {
            const int row = start + 16;
            const float l = v + b_out[row];
            out[row] = l;
            blk[16] = l;
        }
    }
    __syncthreads();

    // tail: wave 0, lanes 0..31 -> per-block (max, sumexp) over n values
    if (tid < 32) {
        const float v = (tid < n) ? blk[tid] : -INFINITY;
        float m = v;
#pragma unroll
        for (int off = 16; off; off >>= 1) m = fmaxf(m, __shfl_xor(m, off));
        float e = (tid < n) ? __expf(v - m) : 0.f;
#pragma unroll
        for (int off = 16; off; off >>= 1) e += __shfl_xor(e, off);
        if (tid == 0) partials[bid] = make_float2(m, e);
    }
}

// Each block redundantly merges all partials (L2-hot, 24 KB) then subtracts
// the log-sum-exp from its 256 output elements.
__global__ __launch_bounds__(256) void k_norm(const float2* __restrict__ partials,
                                              float* __restrict__ out) {
    const int tid = threadIdx.x;
    const int wid = tid >> 6, lane = tid & 63;

    float m = -INFINITY, s = 0.f;
#pragma unroll 4
    for (int i = tid; i < NBL; i += 256) {   // exactly 12 iterations
        const float2 p = partials[i];
        lse_merge(m, s, p.x, p.y);
    }
#pragma unroll
    for (int off = 32; off; off >>= 1) {
        const float mo = __shfl_xor(m, off), so = __shfl_xor(s, off);
        lse_merge(m, s, mo, so);
    }
    __shared__ float cm[4], cs[4], st_sh;
    if (lane == 0) { cm[wid] = m; cs[wid] = s; }
    __syncthreads();
    if (tid == 0) {
        float M = cm[0], S = cs[0];
#pragma unroll
        for (int w = 1; w < 4; ++w) lse_merge(M, S, cm[w], cs[w]);
        st_sh = M + __logf(S);
    }
    __syncthreads();
    const float st = st_sh;
    const int i = blockIdx.x * 256 + tid;
    if (i < V) out[i] -= st;
}

extern "C" void kernel_launch(void* const* d_in, const int* in_sizes, int n_in,
                              void* d_out, int out_size, void* d_ws, size_t ws_size,
                              hipStream_t stream) {
    const int*   token = (const int*)d_in[0];
    const float* h0    = (const float*)d_in[1];
    const float* c0    = (const float*)d_in[2];
    const float* emb   = (const float*)d_in[3];
    const float* W_ih  = (const float*)d_in[4];
    const float* W_hh  = (const float*)d_in[5];
    const float* b_ih  = (const float*)d_in[6];
    const float* b_hh  = (const float*)d_in[7];
    const float* W_out = (const float*)d_in[8];
    const float* b_out = (const float*)d_in[9];

    float* out = (float*)d_out;
    float* ws  = (float*)d_ws;
    float* h1ws      = ws;
    float2* partials = (float2*)(ws + H);

    k_gates_cell<<<H, 256, 0, stream>>>(token, h0, c0, emb, W_ih, W_hh, b_ih, b_hh, out, h1ws);
    k_logits<<<NBL, 256, 0, stream>>>(h1ws, W_out, b_out, out, partials);
    k_norm<<<NB_NORM, 256, 0, stream>>>(partials, out);
}